// Round 1
// baseline (166.105 us; speedup 1.0000x reference)
//
#include <hip/hip_runtime.h>

// LearnedTaskSpecificLinear: out[n,o] = sum_i x[n,i] * W[task_ids[n], i, o]
// x: [2048,512] f32, task_ids: [2048] i32, W: [64,512,512] f32, out: [2048,512] f32
//
// Design (round 1):
//   grid = (8 col-chunks of 64, 64 tasks), block = 64 threads (1 wave)
//   Each block: ballot-compact rows with tid==task into LDS rowlist (deterministic,
//   no atomics, single wave), then GEMM rows x W[task][:, c0:c0+64] with
//   K-tiling (KT=64): Ws tile + transposed xs tile in LDS, each lane owns
//   8 rows x 4 cols of fp32 accumulators (32 acc) so each ds_read_b128 feeds
//   many FMAs. W is read from HBM exactly once across the whole grid.

#define NTASKS   64
#define KDIM     512
#define NDIM     512
#define NCOL     64    // cols per block
#define GROWS    32    // rows per pass
#define KT       64    // k-tile depth
#define XS_STR   36    // padded row stride (words) for transposed xs; %4==0 keeps b128 alignment

__global__ __launch_bounds__(64) void tsl_kernel(
    const float* __restrict__ x,
    const int*   __restrict__ tids,
    const float* __restrict__ W,
    float*       __restrict__ out,
    int n_rows)
{
    const int lane = threadIdx.x;          // 0..63
    const int task = blockIdx.y;           // 0..63
    const int c0   = blockIdx.x * NCOL;    // 0,64,...,448

    __shared__ unsigned short rowlist[2048];   // 4 KB
    __shared__ float Ws[KT][NCOL];             // 16 KB: Ws[kk][c] = W[task][kt+kk][c0+c]
    __shared__ float xs[KT][XS_STR];           // 9 KB:  xs[kk][r] = x[row_r][kt+kk]

    // ---- ballot-compact rows belonging to this task (wave-uniform count) ----
    int count = 0;
    for (int base = 0; base < n_rows; base += 64) {
        const int row = base + lane;
        const bool m = (tids[row] == task);
        const unsigned long long bal = __ballot(m);
        const int rank = __popcll(bal & ((1ull << lane) - 1ull));
        if (m) rowlist[count + rank] = (unsigned short)row;
        count += __popcll(bal);
    }
    __syncthreads();

    if (count == 0) return;

    const int cg4   = (lane & 15) << 2;    // col offset within chunk: 0,4,...,60
    const int rbase = (lane >> 4) << 3;    // row-group base: 0,8,16,24

    const float* Wt = W + (size_t)task * KDIM * NDIM + c0;

    for (int g0 = 0; g0 < count; g0 += GROWS) {
        float acc[8][4];
        #pragma unroll
        for (int j = 0; j < 8; ++j) {
            acc[j][0] = 0.f; acc[j][1] = 0.f; acc[j][2] = 0.f; acc[j][3] = 0.f;
        }

        for (int kt = 0; kt < KDIM; kt += KT) {
            // ---- stage Ws: 64x64 floats, each lane 16 float4 loads (coalesced 256B/16 lanes)
            #pragma unroll
            for (int it = 0; it < 16; ++it) {
                const int idx = it * 64 + lane;        // 0..1023
                const int kk  = idx >> 4;              // 0..63
                const int c4  = (idx & 15) << 2;       // 0..60
                const float4 v = *(const float4*)(Wt + (size_t)(kt + kk) * NDIM + c4);
                *(float4*)&Ws[kk][c4] = v;
            }
            // ---- stage xs transposed: 32 rows x 64 k, each lane 8 float4 loads
            #pragma unroll
            for (int it = 0; it < 8; ++it) {
                const int idx = it * 64 + lane;        // 0..511
                const int r   = idx >> 4;              // 0..31
                const int i4  = (idx & 15) << 2;       // 0..60
                const int rr  = g0 + r;
                const int row = rowlist[(rr < count) ? rr : g0];  // dummy-safe
                const float4 v = *(const float4*)(x + (size_t)row * KDIM + kt + i4);
                xs[i4 + 0][r] = v.x;
                xs[i4 + 1][r] = v.y;
                xs[i4 + 2][r] = v.z;
                xs[i4 + 3][r] = v.w;
            }
            __syncthreads();

            // ---- compute: per i, 3 x ds_read_b128 + 32 FMA
            #pragma unroll 8
            for (int i = 0; i < KT; ++i) {
                const float4 w4 = *(const float4*)&Ws[i][cg4];
                const float4 xa = *(const float4*)&xs[i][rbase];
                const float4 xb = *(const float4*)&xs[i][rbase + 4];
                const float xv[8] = {xa.x, xa.y, xa.z, xa.w, xb.x, xb.y, xb.z, xb.w};
                #pragma unroll
                for (int j = 0; j < 8; ++j) {
                    acc[j][0] = fmaf(xv[j], w4.x, acc[j][0]);
                    acc[j][1] = fmaf(xv[j], w4.y, acc[j][1]);
                    acc[j][2] = fmaf(xv[j], w4.z, acc[j][2]);
                    acc[j][3] = fmaf(xv[j], w4.w, acc[j][3]);
                }
            }
            __syncthreads();
        }

        // ---- epilogue: each lane stores up to 8 float4
        #pragma unroll
        for (int j = 0; j < 8; ++j) {
            const int rr = g0 + rbase + j;
            if (rr < count) {
                const int row = rowlist[rr];
                float4 o;
                o.x = acc[j][0]; o.y = acc[j][1]; o.z = acc[j][2]; o.w = acc[j][3];
                *(float4*)(out + (size_t)row * NDIM + c0 + cg4) = o;
            }
        }
    }
}

extern "C" void kernel_launch(void* const* d_in, const int* in_sizes, int n_in,
                              void* d_out, int out_size, void* d_ws, size_t ws_size,
                              hipStream_t stream) {
    const float* x    = (const float*)d_in[0];
    const int*   tids = (const int*)d_in[1];
    const float* W    = (const float*)d_in[2];
    float*       out  = (float*)d_out;
    const int n_rows  = in_sizes[1];   // 2048

    dim3 grid(NDIM / NCOL, NTASKS);    // (8, 64)
    dim3 block(64);
    tsl_kernel<<<grid, block, 0, stream>>>(x, tids, W, out, n_rows);
}

// Round 2
// 116.112 us; speedup vs baseline: 1.4306x; 1.4306x over previous
//
#include <hip/hip_runtime.h>

// LearnedTaskSpecificLinear: out[n,o] = sum_i x[n,i] * W[task_ids[n], i, o]
// x: [2048,512] f32, task_ids: [2048] i32, W: [64,512,512] f32, out: [2048,512] f32
//
// Round 2: MFMA-f16 + occupancy fix.
//   grid = (8 col-chunks of 64, 64 tasks) = 512 blocks x 256 threads (4 waves).
//   Waves split K: wave w owns k in [w*128, w*128+128), staged in WAVE-PRIVATE
//   LDS tiles (no __syncthreads in the K-loop; intra-wave waitcnt only).
//   W tile fp32 -> f16 converted in-register, written k-minor (transposed) via
//   packed f16x4 b64 LDS writes. x rows gathered via ballot-compacted rowlist.
//   GROWS=64 rows/pass (covers max statistical rows/task in ONE pass -> W read
//   exactly once from HBM). mfma_f32_16x16x32_f16, acc 4x4 tiles of 16x16.
//   Cross-wave K-reduction through LDS (aliased over the tiles) at the end.

#define KDIM   512
#define NDIM   512
#define NCOL   64
#define GROWS  64
#define TSTR   40      // f16 elements per tile row (80 B): 20 words -> 2-way banks, 16B-aligned

typedef _Float16 __attribute__((ext_vector_type(8))) f16x8;
typedef _Float16 __attribute__((ext_vector_type(4))) f16x4;
typedef float    __attribute__((ext_vector_type(4))) f32x4;

__global__ __launch_bounds__(256) void tsl_mfma(
    const float* __restrict__ x,
    const int*   __restrict__ tids,
    const float* __restrict__ W,
    float*       __restrict__ out,
    int n_rows)
{
    const int tid  = threadIdx.x;
    const int lane = tid & 63;
    const int wv   = tid >> 6;           // wave 0..3
    const int task = blockIdx.y;
    const int c0   = blockIdx.x * NCOL;

    __shared__ unsigned short rowlist[2048];          // 4 KB
    __shared__ __align__(16) char smem[40960];        // tiles (4x10240) / red (32768) aliased

    _Float16* Wt = (_Float16*)(smem + wv * 10240);          // [64 cols][TSTR]
    _Float16* xs = (_Float16*)(smem + wv * 10240 + 5120);   // [64 rows][TSTR]
    float*    red = (float*)smem;                           // [4][32*64]

    // ---- ballot-compact rows of this task (every wave computes count; wave 0 writes) ----
    int count = 0;
    for (int base = 0; base < n_rows; base += 64) {
        const int row = base + lane;
        const bool m = (row < n_rows) && (tids[row] == task);
        const unsigned long long bal = __ballot(m);
        const int rank = __popcll(bal & ((1ull << lane) - 1ull));
        if (wv == 0 && m) rowlist[count + rank] = (unsigned short)row;
        count += __popcll(bal);
    }
    __syncthreads();
    if (count == 0) return;

    const int ml = lane & 15;     // fragment row/col index
    const int q  = lane >> 4;     // quad 0..3
    const float* Wg = W + (size_t)task * KDIM * NDIM + c0;
    const int kw = wv * 128;      // this wave's K range

    for (int g0 = 0; g0 < count; g0 += GROWS) {
        f32x4 acc[4][4] = {};     // 4 row-tiles x 4 col-tiles of 16x16

        #pragma unroll
        for (int kt = 0; kt < 4; ++kt) {
            const int k0 = kw + kt * 32;

            // ---- stage W tile [32 k][64 c] fp32 -> Wt[c][k] f16 (transposed, packed b64)
            #pragma unroll
            for (int p = 0; p < 2; ++p) {
                const int kb = p * 16 + q * 4;
                const float* gp = Wg + (size_t)(k0 + kb) * NDIM + ml * 4;
                const float4 r0 = *(const float4*)(gp);
                const float4 r1 = *(const float4*)(gp + NDIM);
                const float4 r2 = *(const float4*)(gp + 2 * NDIM);
                const float4 r3 = *(const float4*)(gp + 3 * NDIM);
                _Float16* wp = Wt + (ml * 4) * TSTR + kb;
                f16x4 v0 = {(_Float16)r0.x, (_Float16)r1.x, (_Float16)r2.x, (_Float16)r3.x};
                f16x4 v1 = {(_Float16)r0.y, (_Float16)r1.y, (_Float16)r2.y, (_Float16)r3.y};
                f16x4 v2 = {(_Float16)r0.z, (_Float16)r1.z, (_Float16)r2.z, (_Float16)r3.z};
                f16x4 v3 = {(_Float16)r0.w, (_Float16)r1.w, (_Float16)r2.w, (_Float16)r3.w};
                *(f16x4*)(wp)             = v0;
                *(f16x4*)(wp + TSTR)      = v1;
                *(f16x4*)(wp + 2 * TSTR)  = v2;
                *(f16x4*)(wp + 3 * TSTR)  = v3;
            }

            // ---- stage x tile [64 rows][32 k] -> xs[r][k] f16 (natural k-minor)
            #pragma unroll
            for (int u = 0; u < 8; ++u) {
                const int r  = u * 8 + (lane >> 3);
                const int kq = (lane & 7) * 4;
                const int rr = g0 + r;
                const int row = rowlist[(rr < count) ? rr : g0];
                const float4 v = *(const float4*)(x + (size_t)row * KDIM + k0 + kq);
                f16x4 h = {(_Float16)v.x, (_Float16)v.y, (_Float16)v.z, (_Float16)v.w};
                *(f16x4*)(xs + r * TSTR + kq) = h;
            }

            // ---- fragments + 16 mfma (K=32 consumed whole per tile)
            f16x8 af[4], bf[4];
            #pragma unroll
            for (int rt = 0; rt < 4; ++rt)
                af[rt] = *(const f16x8*)(xs + (rt * 16 + ml) * TSTR + q * 8);
            #pragma unroll
            for (int ct = 0; ct < 4; ++ct)
                bf[ct] = *(const f16x8*)(Wt + (ct * 16 + ml) * TSTR + q * 8);
            #pragma unroll
            for (int rt = 0; rt < 4; ++rt)
                #pragma unroll
                for (int ct = 0; ct < 4; ++ct)
                    acc[rt][ct] = __builtin_amdgcn_mfma_f32_16x16x32_f16(
                        af[rt], bf[ct], acc[rt][ct], 0, 0, 0);
        }

        // ---- cross-wave K-reduction through LDS, 32 rows per half ----
        #pragma unroll
        for (int h = 0; h < 2; ++h) {
            __syncthreads();   // tiles (h=0) / previous reduce reads (h=1) are done
            #pragma unroll
            for (int rt2 = 0; rt2 < 2; ++rt2) {
                const int rt = h * 2 + rt2;
                #pragma unroll
                for (int ct = 0; ct < 4; ++ct)
                    #pragma unroll
                    for (int rg = 0; rg < 4; ++rg) {
                        const int row = rt2 * 16 + q * 4 + rg;   // C/D: row=quad*4+reg
                        const int col = ct * 16 + ml;            //       col=lane&15
                        red[wv * 2048 + row * 64 + col] = acc[rt][ct][rg];
                    }
            }
            __syncthreads();
            // reduce 4 partials + store (fully coalesced: idx contiguous over threads)
            #pragma unroll
            for (int t2 = 0; t2 < 2; ++t2) {
                const int idx = t2 * 1024 + tid * 4;
                const float4 a0 = *(const float4*)&red[idx];
                const float4 a1 = *(const float4*)&red[2048 + idx];
                const float4 a2 = *(const float4*)&red[4096 + idx];
                const float4 a3 = *(const float4*)&red[6144 + idx];
                float4 s;
                s.x = a0.x + a1.x + a2.x + a3.x;
                s.y = a0.y + a1.y + a2.y + a3.y;
                s.z = a0.z + a1.z + a2.z + a3.z;
                s.w = a0.w + a1.w + a2.w + a3.w;
                const int r  = h * 32 + (idx >> 6);
                const int c  = idx & 63;
                const int rr = g0 + r;
                if (rr < count)
                    *(float4*)(out + (size_t)rowlist[rr] * NDIM + c0 + c) = s;
            }
        }
        __syncthreads();   // red region becomes tiles again next pass
    }
}

extern "C" void kernel_launch(void* const* d_in, const int* in_sizes, int n_in,
                              void* d_out, int out_size, void* d_ws, size_t ws_size,
                              hipStream_t stream) {
    const float* x    = (const float*)d_in[0];
    const int*   tids = (const int*)d_in[1];
    const float* W    = (const float*)d_in[2];
    float*       out  = (float*)d_out;
    const int n_rows  = in_sizes[1];   // 2048

    dim3 grid(NDIM / NCOL, 64);        // (8 col-chunks, 64 tasks)
    dim3 block(256);
    tsl_mfma<<<grid, block, 0, stream>>>(x, tids, W, out, n_rows);
}